// Round 4
// baseline (276.183 us; speedup 1.0000x reference)
//
#include <hip/hip_runtime.h>
#include <math.h>

// Problem constants (fixed by reference setup_inputs)
#define NTOT 100
#define NQ   75
#define NP   25
#define CC   128
#define TT   8
#define VV   25
#define NCLS 5
#define NSUP 5
#define NQRY 15
#define ROW  (TT*VV*CC)   // 25600 floats per sample
#define TILE (VV*CC)      // 3200 floats per (n,t)
#define ROWS_Q 20000
#define ROWS_S 5000
#define RB_Q 625
#define RB_S 157

typedef __attribute__((ext_vector_type(8))) short short8;
typedef __attribute__((ext_vector_type(16))) float f32x16;

__device__ __forceinline__ ushort f2bf(float f) {
    uint u = __float_as_uint(f);
    u += 0x7FFFu + ((u >> 16) & 1u);   // RNE
    return (ushort)(u >> 16);
}
__device__ __forceinline__ float bf2f(uint u16v) {
    return __uint_as_float(u16v << 16);
}

// ============ kernel 1: prep ============
// blocks 0..199 : gather half-sample (100 tv rows) -> catC bf16 + bf16 A-frags
// blocks 200..203: weight -> bf16 B-frags; 203 also zeros supp-frag pad
// block 204     : zero proto
__global__ __launch_bounds__(256) void k_prep(
    const float* __restrict__ input, const int* __restrict__ target,
    const float* __restrict__ Wq, const float* __restrict__ Wk,
    const float* __restrict__ Wv, const float* __restrict__ Wo,
    ushort* __restrict__ catQbf, ushort* __restrict__ catSbf,
    ushort* __restrict__ Wfrag, ushort* __restrict__ catC,
    float* __restrict__ proto) {
    __shared__ float smp[100 * 129];   // [tt][c], stride 129 conflict-free
    __shared__ int targ[NTOT];
    __shared__ int order[NTOT];
    int b = blockIdx.x, tid = threadIdx.x;

    if (b < 200) {
        int n = b >> 1, hf = b & 1;
        if (tid < NTOT) targ[tid] = target[tid];
        __syncthreads();
        if (tid < NTOT) {
            int ti = targ[tid], rank = 0;
            for (int j = 0; j < NTOT; ++j) {
                int tj = targ[j];
                rank += (tj < ti) || (tj == ti && j < tid);
            }
            order[rank] = tid;
        }
        __syncthreads();
        int src;
        if (n < NQ) { int m = n / NQRY, qq = n - m * NQRY; src = order[m * 20 + NSUP + qq]; }
        else        { int i = n - NQ; int m = i / NSUP, s = i - m * NSUP; src = order[m * 20 + s]; }

        const float* in = input + (size_t)src * ROW + hf * 100;
        for (int idx = tid; idx < 12800; idx += 256) {
            int c = idx / 100, tt = idx - c * 100;      // contiguous 400B runs
            smp[tt * 129 + c] = in[c * 200 + tt];
        }
        __syncthreads();
        // catC bf16 [n][tv][c], packed u32 writes (coalesced)
        uint* cc = (uint*)catC + ((size_t)n * 200 + hf * 100) * 64;
        for (int e2 = tid; e2 < 6400; e2 += 256) {
            int r = e2 >> 6, c2 = e2 & 63;
            float f0 = smp[r * 129 + c2 * 2], f1 = smp[r * 129 + c2 * 2 + 1];
            cc[r * 64 + c2] = (uint)f2bf(f0) | ((uint)f2bf(f1) << 16);
        }
        // bf16 A-frag writes
        bool isSup = (n >= NQ);
        for (int o = tid; o < 1600; o += 256) {
            int k8 = o / 100, tt = o - k8 * 100;
            int base = tt * 129 + k8 * 8;
            uint4 pk;
            pk.x = (uint)f2bf(smp[base+0]) | ((uint)f2bf(smp[base+1]) << 16);
            pk.y = (uint)f2bf(smp[base+2]) | ((uint)f2bf(smp[base+3]) << 16);
            pk.z = (uint)f2bf(smp[base+4]) | ((uint)f2bf(smp[base+5]) << 16);
            pk.w = (uint)f2bf(smp[base+6]) | ((uint)f2bf(smp[base+7]) << 16);
            int row = n * 200 + hf * 100 + tt;
            size_t dst = (((size_t)(row >> 5) * 8 + (k8 >> 1)) * 64 + ((row & 31) + 32 * (k8 & 1))) * 8;
            *(uint4*)(catQbf + dst) = pk;
            if (isSup) {
                int r2 = (n - NQ) * 200 + hf * 100 + tt;
                size_t dst2 = (((size_t)(r2 >> 5) * 8 + (k8 >> 1)) * 64 + ((r2 & 31) + 32 * (k8 & 1))) * 8;
                *(uint4*)(catSbf + dst2) = pk;
            }
        }
    } else if (b < 204) {
        int wi = b - 200;
        const float* W = (wi == 0) ? Wq : (wi == 1) ? Wk : (wi == 2) ? Wv : Wo;
        ushort* dstW = Wfrag + (size_t)wi * 16384;
        for (int o = tid; o < 2048; o += 256) {
            int k8 = o >> 7, c = o & 127;
            uint4 pk;
            float f0 = W[(k8*8+0)*128 + c], f1 = W[(k8*8+1)*128 + c];
            float f2 = W[(k8*8+2)*128 + c], f3 = W[(k8*8+3)*128 + c];
            float f4 = W[(k8*8+4)*128 + c], f5 = W[(k8*8+5)*128 + c];
            float f6 = W[(k8*8+6)*128 + c], f7 = W[(k8*8+7)*128 + c];
            pk.x = (uint)f2bf(f0) | ((uint)f2bf(f1) << 16);
            pk.y = (uint)f2bf(f2) | ((uint)f2bf(f3) << 16);
            pk.z = (uint)f2bf(f4) | ((uint)f2bf(f5) << 16);
            pk.w = (uint)f2bf(f6) | ((uint)f2bf(f7) << 16);
            size_t dst = ((size_t)((c >> 5) * 8 + (k8 >> 1)) * 64 + ((c & 31) + 32 * (k8 & 1))) * 8;
            *(uint4*)(dstW + dst) = pk;
        }
        if (wi == 3) {
            uint4 z = make_uint4(0, 0, 0, 0);
            for (int o = tid; o < 512; o += 256) {
                int ks = o >> 6, l = o & 63;
                if ((l & 31) >= 8)
                    *(uint4*)(catSbf + (((size_t)156 * 8 + ks) * 64 + l) * 8) = z;
            }
        }
    } else {
        for (int i = tid; i < NCLS * ROW; i += 256) proto[i] = 0.f;
    }
}

// ============ kernel 2: projections via MFMA (unchanged structure) ============
__global__ __launch_bounds__(256) void k_proj(
    const ushort* __restrict__ catQbf, const ushort* __restrict__ catSbf,
    const ushort* __restrict__ Wfrag, const float* __restrict__ bq,
    const float* __restrict__ bk, const float* __restrict__ bv,
    ushort* __restrict__ Qf, ushort* __restrict__ Kf, ushort* __restrict__ Vf) {
    __shared__ ushort Vt[128 * 136];
    int b = blockIdx.x, tid = threadIdx.x;
    int w = tid >> 6, lane = tid & 63;
    int typ, rb0, nrb;
    if (b < 157)      { typ = 0; rb0 = b * 4;         nrb = RB_Q; }
    else if (b < 197) { typ = 1; rb0 = (b - 157) * 4; nrb = RB_S; }
    else              { typ = 2; rb0 = (b - 197) * 4; nrb = RB_S; }
    int rowblk = rb0 + w;
    bool act = rowblk < nrb;
    const ushort* src = (typ == 0) ? catQbf : catSbf;
    const ushort* Wf = Wfrag + (size_t)typ * 16384;
    const float* bias = (typ == 0) ? bq : (typ == 1) ? bk : bv;
    int rlimit = (typ == 0) ? ROWS_Q : ROWS_S;

    short8 af[8];
    if (act) {
        const ushort* ap = src + (size_t)rowblk * 4096 + lane * 8;
        #pragma unroll
        for (int ks = 0; ks < 8; ++ks) af[ks] = *(const short8*)(ap + ks * 512);
    }
    #pragma unroll
    for (int ct = 0; ct < 4; ++ct) {
        f32x16 Cm;
        #pragma unroll
        for (int r = 0; r < 16; ++r) Cm[r] = 0.f;
        if (act) {
            const ushort* bp = Wf + (size_t)(ct * 8) * 512 + lane * 8;
            #pragma unroll
            for (int ks = 0; ks < 8; ++ks) {
                short8 bf_ = *(const short8*)(bp + ks * 512);
                Cm = __builtin_amdgcn_mfma_f32_32x32x16_bf16(af[ks], bf_, Cm, 0, 0, 0);
            }
            float bcol = bias[ct * 32 + (lane & 31)];
            if (typ <= 1) {
                ushort* dstB = (typ == 0) ? Qf : Kf;
                #pragma unroll
                for (int r = 0; r < 16; ++r) {
                    int row = rowblk * 32 + (r & 3) + 8 * (r >> 2) + 4 * (lane >> 5);
                    if (row < rlimit) {
                        int c = ct * 32 + (lane & 31);
                        int st = row / 25, vv = row - st * 25;
                        size_t dst = (((size_t)st * 8 + (c >> 4)) * 64 + (vv + 32 * ((c >> 3) & 1))) * 8 + (c & 7);
                        dstB[dst] = f2bf(Cm[r] + bcol);
                    }
                }
            } else {
                #pragma unroll
                for (int r = 0; r < 16; ++r) {
                    int lrow = w * 32 + (r & 3) + 8 * (r >> 2) + 4 * (lane >> 5);
                    Vt[lrow * 136 + ct * 32 + (lane & 31)] = f2bf(Cm[r] + bcol);
                }
            }
        }
    }
    if (typ == 2) {
        __syncthreads();
        const ushort* WoF = Wfrag + (size_t)3 * 16384;
        short8 a2[8];
        if (act) {
            #pragma unroll
            for (int ks = 0; ks < 8; ++ks)
                a2[ks] = *(const short8*)(Vt + (w * 32 + (lane & 31)) * 136 + ks * 16 + (lane >> 5) * 8);
        }
        #pragma unroll
        for (int ct = 0; ct < 4; ++ct) {
            if (act) {
                f32x16 Cm;
                #pragma unroll
                for (int r = 0; r < 16; ++r) Cm[r] = 0.f;
                const ushort* bp = WoF + (size_t)(ct * 8) * 512 + lane * 8;
                #pragma unroll
                for (int ks = 0; ks < 8; ++ks) {
                    short8 bf_ = *(const short8*)(bp + ks * 512);
                    Cm = __builtin_amdgcn_mfma_f32_32x32x16_bf16(a2[ks], bf_, Cm, 0, 0, 0);
                }
                #pragma unroll
                for (int r = 0; r < 16; ++r) {
                    int row = rowblk * 32 + (r & 3) + 8 * (r >> 2) + 4 * (lane >> 5);
                    if (row < ROWS_S) {
                        int c = ct * 32 + (lane & 31);
                        int tile = row / 25, vv = row - tile * 25;
                        size_t dst = ((((size_t)tile * 4 + ct) * 2 + (vv >> 4)) * 64
                                      + ((c & 31) + 32 * ((vv & 15) >> 3))) * 8 + (vv & 7);
                        Vf[dst] = f2bf(Cm[r]);
                    }
                }
            }
        }
    }
}

// ============ kernel 3: MFMA fused attention + residual + LN ============
// 800 blocks = one per (n,t); 4 waves split m 7/6/6/6; no barriers in m-loop.
// Emits raw LN sums; support blocks atomicAdd *0.2 into proto.
__global__ __launch_bounds__(256, 3) void k_attn(
    const ushort* __restrict__ Qf, const ushort* __restrict__ Kf,
    const ushort* __restrict__ Vf, const ushort* __restrict__ catC,
    const float* __restrict__ bo, float* __restrict__ att,
    float* __restrict__ proto) {
    __shared__ float catb[25 * 129];          // stride 129: conflict-free scalar reads
    __shared__ float red[2][50][65];          // reduce scratch; ALIASED by pfrag in m-loop
    ushort* pfragU = (ushort*)red;            // [4 wv][2 ks][64 lane][8] = 8 KB < 26 KB

    int pair = blockIdx.x;                    // n*8 + t
    int n = pair >> 3, t = pair & 7;
    int tid = threadIdx.x;
    int wv = tid >> 6, lane = tid & 63;
    int q = lane & 31, half = lane >> 5;

    // stage residual tile: catb = bf16(catC) + bo
    {
        const uint* cc = (const uint*)catC + (size_t)pair * 1600;
        for (int i2 = tid; i2 < 1600; i2 += 256) {
            uint u = cc[i2];
            int r = i2 >> 6, c2 = (i2 & 63) * 2;
            catb[r * 129 + c2]     = bf2f(u & 0xffffu) + bo[c2];
            catb[r * 129 + c2 + 1] = bf2f(u >> 16) + bo[c2 + 1];
        }
    }
    // zero this wave's P-frag (aliased memory; key>=25 slots stay 0)
    {
        uint4 z = make_uint4(0, 0, 0, 0);
        *(uint4*)&pfragU[(((wv * 2 + 0) * 64) + lane) * 8] = z;
        *(uint4*)&pfragU[(((wv * 2 + 1) * 64) + lane) * 8] = z;
    }
    short8 qf[8];
    {
        const ushort* qp = Qf + (size_t)pair * 4096 + lane * 8;
        #pragma unroll
        for (int ks = 0; ks < 8; ++ks) qf[ks] = *(const short8*)(qp + ks * 512);
    }
    __syncthreads();

    int qc = q < 25 ? q : 24;
    float attsum[64];
    #pragma unroll
    for (int i = 0; i < 64; ++i) attsum[i] = 0.f;
    float Csc = 0.f;                          // sum over m of (-mu*rs)

    const float CEXP = (float)(1.4426950408889634 * 0.08838834764831845);

    for (int m = wv; m < 25; m += 4) {
        const ushort* kp = Kf + ((size_t)(m * 8 + t)) * 4096 + lane * 8;
        const ushort* vp = Vf + ((size_t)(m * 8 + t)) * 4096 + lane * 8;
        short8 kf[8];
        #pragma unroll
        for (int ks = 0; ks < 8; ++ks) kf[ks] = *(const short8*)(kp + ks * 512);
        f32x16 S;
        #pragma unroll
        for (int r = 0; r < 16; ++r) S[r] = 0.f;
        #pragma unroll
        for (int ks = 0; ks < 8; ++ks)
            S = __builtin_amdgcn_mfma_f32_32x32x16_bf16(kf[ks], qf[ks], S, 0, 0, 0);

        float p[16], mx = -3e38f;
        #pragma unroll
        for (int r = 0; r < 16; ++r) {
            int key = (r & 3) + 8 * (r >> 2) + 4 * half;
            float v = (key < 25) ? S[r] : -3e38f;
            p[r] = v; mx = fmaxf(mx, v);
        }
        mx = fmaxf(mx, __shfl_xor(mx, 32));
        float sum = 0.f;
        #pragma unroll
        for (int r = 0; r < 16; ++r) { p[r] = exp2f((p[r] - mx) * CEXP); sum += p[r]; }
        sum += __shfl_xor(sum, 32);
        float inv = 1.f / sum;

        #pragma unroll
        for (int r = 0; r < 16; ++r) {
            int key = (r & 3) + 8 * (r >> 2) + 4 * half;
            if (key < 25)
                pfragU[(((wv * 2 + (key >> 4)) * 64) + (q + 32 * ((key >> 3) & 1))) * 8 + (key & 7)]
                    = f2bf(p[r] * inv);
        }
        short8 pb0 = *(const short8*)&pfragU[(((wv * 2 + 0) * 64) + lane) * 8];
        short8 pb1 = *(const short8*)&pfragU[(((wv * 2 + 1) * 64) + lane) * 8];

        f32x16 ctx[4];
        #pragma unroll
        for (int mt = 0; mt < 4; ++mt) {
            short8 v0 = *(const short8*)(vp + mt * 1024);
            short8 v1 = *(const short8*)(vp + mt * 1024 + 512);
            f32x16 c;
            #pragma unroll
            for (int r = 0; r < 16; ++r) c[r] = 0.f;
            c = __builtin_amdgcn_mfma_f32_32x32x16_bf16(v0, pb0, c, 0, 0, 0);
            c = __builtin_amdgcn_mfma_f32_32x32x16_bf16(v1, pb1, c, 0, 0, 0);
            ctx[mt] = c;
        }

        float s1 = 0.f, s2 = 0.f;
        #pragma unroll
        for (int mt = 0; mt < 4; ++mt) {
            #pragma unroll
            for (int r = 0; r < 16; ++r) {
                int c = mt * 32 + (r & 3) + 8 * (r >> 2) + 4 * half;
                float xv = ctx[mt][r] + catb[qc * 129 + c];
                ctx[mt][r] = xv;
                s1 += xv; s2 = fmaf(xv, xv, s2);
            }
        }
        s1 += __shfl_xor(s1, 32); s2 += __shfl_xor(s2, 32);
        float mu = s1 * (1.f / 128.f);
        float var = s2 * (1.f / 128.f) - mu * mu;
        var = fmaxf(var, 0.f);
        float rs = rsqrtf(var + 1e-12f);
        #pragma unroll
        for (int i = 0; i < 64; ++i)
            attsum[i] = fmaf(ctx[i >> 4][i & 15], rs, attsum[i]);
        Csc = fmaf(-mu, rs, Csc);
    }

    // ---- 2-stage pairwise cross-wave reduction (compact: 50 live lanes) ----
    __syncthreads();   // all waves done with m-loop; pfrag alias now dead
    int s = half * 25 + q;
    bool act = q < 25;
    if ((wv == 1 || wv == 3) && act) {
        float (*rg)[65] = red[wv >> 1];
        #pragma unroll
        for (int i = 0; i < 64; ++i) rg[s][i] = attsum[i];
        rg[s][64] = Csc;
    }
    __syncthreads();
    if ((wv == 0 || wv == 2) && act) {
        float (*rg)[65] = red[wv >> 1];
        #pragma unroll
        for (int i = 0; i < 64; ++i) attsum[i] += rg[s][i];
        Csc += rg[s][64];
    }
    __syncthreads();
    if (wv == 2 && act) {
        #pragma unroll
        for (int i = 0; i < 64; ++i) red[0][s][i] = attsum[i];
        red[0][s][64] = Csc;
    }
    __syncthreads();
    if (wv == 0 && act) {
        #pragma unroll
        for (int i = 0; i < 64; ++i) attsum[i] += red[0][s][i];
        Csc += red[0][s][64];
        if (n < NQ) {
            float* ap = att + (size_t)pair * TILE + q * 128;
            #pragma unroll
            for (int mt = 0; mt < 4; ++mt) {
                #pragma unroll
                for (int rg4 = 0; rg4 < 4; ++rg4) {
                    int c0 = mt * 32 + 8 * rg4 + 4 * half;
                    int i0 = mt * 16 + rg4 * 4;
                    float4 o;
                    o.x = attsum[i0 + 0] + Csc; o.y = attsum[i0 + 1] + Csc;
                    o.z = attsum[i0 + 2] + Csc; o.w = attsum[i0 + 3] + Csc;
                    *(float4*)&ap[c0] = o;
                }
            }
        } else {
            int cls = (n - NQ) / NSUP;
            float* pp = proto + (size_t)cls * ROW + t * TILE + q * 128;
            #pragma unroll
            for (int mt = 0; mt < 4; ++mt) {
                #pragma unroll
                for (int r = 0; r < 16; ++r) {
                    int c = mt * 32 + (r & 3) + 8 * (r >> 2) + 4 * half;
                    atomicAdd(&pp[c], (attsum[mt * 16 + r] + Csc) * 0.2f);
                }
            }
        }
    }
}

// ============ kernel 4: distances, one block per (query, class) ============
__global__ __launch_bounds__(256) void k_dist(
    const float* __restrict__ att, const float* __restrict__ proto,
    const float* __restrict__ ln_g, float* __restrict__ dist) {
    int b = blockIdx.x;
    int i = b / 5, j = b - 5 * i;
    const float4* a = (const float4*)(att + (size_t)i * ROW);
    const float4* p = (const float4*)(proto + (size_t)j * ROW);
    float d = 0.f;
    for (int e4 = threadIdx.x; e4 < 6400; e4 += 256) {
        float4 av = a[e4], pv = p[e4];
        float4 g4 = *(const float4*)(ln_g + (e4 & 31) * 4);
        float dx = av.x - pv.x, dy = av.y - pv.y;
        float dz = av.z - pv.z, dw = av.w - pv.w;
        d = fmaf(g4.x * g4.x, dx * dx, d);
        d = fmaf(g4.y * g4.y, dy * dy, d);
        d = fmaf(g4.z * g4.z, dz * dz, d);
        d = fmaf(g4.w * g4.w, dw * dw, d);
    }
    #pragma unroll
    for (int msk = 32; msk >= 1; msk >>= 1) d += __shfl_xor(d, msk);
    __shared__ float part[4];
    int lane = threadIdx.x & 63, wv = threadIdx.x >> 6;
    if (lane == 0) part[wv] = d;
    __syncthreads();
    if (threadIdx.x == 0)
        dist[b] = (part[0] + part[1] + part[2] + part[3]) * (1.f / 625.f);
}

// ============ kernel 5: log-softmax loss + accuracy ============
__global__ void k_loss(const float* __restrict__ dist, float* __restrict__ out) {
    int i = threadIdx.x;   // 128 threads, 75 active
    float li = 0.f, ok = 0.f;
    if (i < NQ) {
        float dd[5];
        #pragma unroll
        for (int j = 0; j < 5; ++j) dd[j] = dist[i * 5 + j];
        int cls = i / NQRY;
        float mind = dd[0];
        int best = 0;
        #pragma unroll
        for (int j = 1; j < 5; ++j) {
            if (dd[j] < mind) mind = dd[j];
            if (dd[j] < dd[best]) best = j;   // first-min == argmax(-d)
        }
        float sume = 0.f;
        #pragma unroll
        for (int j = 0; j < 5; ++j) sume += expf(mind - dd[j]);
        float lse = logf(sume) - mind;
        li = dd[cls] + lse;
        ok = (best == cls) ? 1.f : 0.f;
    }
    #pragma unroll
    for (int msk = 32; msk >= 1; msk >>= 1) {
        li += __shfl_xor(li, msk);
        ok += __shfl_xor(ok, msk);
    }
    __shared__ float pl[2], po[2];
    int wv = i >> 6, lane = i & 63;
    if (lane == 0) { pl[wv] = li; po[wv] = ok; }
    __syncthreads();
    if (i == 0) {
        out[0] = (pl[0] + pl[1]) / 75.f;
        out[1] = (po[0] + po[1]) / 75.f;
    }
}

extern "C" void kernel_launch(void* const* d_in, const int* in_sizes, int n_in,
                              void* d_out, int out_size, void* d_ws, size_t ws_size,
                              hipStream_t stream) {
    const float* input = (const float*)d_in[0];
    const float* Wq   = (const float*)d_in[1];
    const float* bq   = (const float*)d_in[2];
    const float* Wk   = (const float*)d_in[3];
    const float* bk   = (const float*)d_in[4];
    const float* Wv   = (const float*)d_in[5];
    const float* bv   = (const float*)d_in[6];
    const float* Wo   = (const float*)d_in[7];
    const float* bo   = (const float*)d_in[8];
    const float* ln_g = (const float*)d_in[9];
    const float* ln_b = (const float*)d_in[10];  // cancels in the distance
    const int* target = (const int*)d_in[11];
    float* out = (float*)d_out;
    (void)ln_b;

    float* ws = (float*)d_ws;
    ushort* catQbf = (ushort*)ws;                            // 2,560,000 u16
    ushort* catSbf = catQbf + (size_t)RB_Q * 4096;           //   643,072
    ushort* Wfrag  = catSbf + (size_t)RB_S * 4096;           //    65,536
    ushort* catC   = Wfrag + 65536;                          // 2,560,000
    ushort* Qf     = catC + 2560000;                         // 3,276,800
    ushort* Kf     = Qf + 3276800;                           //   819,200
    ushort* Vf     = Kf + 819200;                            //   819,200
    float*  att    = (float*)(Vf + 819200);                  // 75*25600 fp32
    float*  proto  = att + 1920000;                          // 128,000
    float*  distb  = proto + 128000;                         // 375
    // total ~29.7 MB

    k_prep<<<205, 256, 0, stream>>>(input, target, Wq, Wk, Wv, Wo,
                                    catQbf, catSbf, Wfrag, catC, proto);
    k_proj<<<237, 256, 0, stream>>>(catQbf, catSbf, Wfrag, bq, bk, bv, Qf, Kf, Vf);
    k_attn<<<800, 256, 0, stream>>>(Qf, Kf, Vf, catC, bo, att, proto);
    k_dist<<<375, 256, 0, stream>>>(att, proto, ln_g, distb);
    k_loss<<<1, 128, 0, stream>>>(distb, out);
}

// Round 5
// 187.336 us; speedup vs baseline: 1.4743x; 1.4743x over previous
//
#include <hip/hip_runtime.h>
#include <math.h>

// Problem constants (fixed by reference setup_inputs)
#define NTOT 100
#define NQ   75
#define NP   25
#define CC   128
#define TT   8
#define VV   25
#define NCLS 5
#define NSUP 5
#define NQRY 15
#define ROW  (TT*VV*CC)   // 25600 floats per sample
#define TILE (VV*CC)      // 3200 floats per (n,t)
#define ROWS_Q 20000
#define ROWS_S 5000
#define RB_Q 625
#define RB_S 157

typedef __attribute__((ext_vector_type(8))) short short8;
typedef __attribute__((ext_vector_type(16))) float f32x16;

__device__ __forceinline__ ushort f2bf(float f) {
    uint u = __float_as_uint(f);
    u += 0x7FFFu + ((u >> 16) & 1u);   // RNE
    return (ushort)(u >> 16);
}
__device__ __forceinline__ float bf2f(uint u16v) {
    return __uint_as_float(u16v << 16);
}

// ============ kernel 1: prep ============
// blocks 0..199 : gather half-sample (100 tv rows) -> catC bf16 + bf16 A-frags
// blocks 200..203: weight -> bf16 B-frags; 203 also zeros supp-frag pad
// block 204     : zero proto + ticket counter
__global__ __launch_bounds__(256) void k_prep(
    const float* __restrict__ input, const int* __restrict__ target,
    const float* __restrict__ Wq, const float* __restrict__ Wk,
    const float* __restrict__ Wv, const float* __restrict__ Wo,
    ushort* __restrict__ catQbf, ushort* __restrict__ catSbf,
    ushort* __restrict__ Wfrag, ushort* __restrict__ catC,
    float* __restrict__ proto, int* __restrict__ counter) {
    __shared__ float smp[100 * 129];   // [tt][c], stride 129 conflict-free
    __shared__ int targ[NTOT];
    __shared__ int order[NTOT];
    int b = blockIdx.x, tid = threadIdx.x;

    if (b < 200) {
        int n = b >> 1, hf = b & 1;
        if (tid < NTOT) targ[tid] = target[tid];
        __syncthreads();
        if (tid < NTOT) {
            int ti = targ[tid], rank = 0;
            for (int j = 0; j < NTOT; ++j) {
                int tj = targ[j];
                rank += (tj < ti) || (tj == ti && j < tid);
            }
            order[rank] = tid;
        }
        __syncthreads();
        int src;
        if (n < NQ) { int m = n / NQRY, qq = n - m * NQRY; src = order[m * 20 + NSUP + qq]; }
        else        { int i = n - NQ; int m = i / NSUP, s = i - m * NSUP; src = order[m * 20 + s]; }

        const float* in = input + (size_t)src * ROW + hf * 100;
        for (int idx = tid; idx < 12800; idx += 256) {
            int c = idx / 100, tt = idx - c * 100;      // contiguous 400B runs
            smp[tt * 129 + c] = in[c * 200 + tt];
        }
        __syncthreads();
        // catC bf16 [n][tv][c], packed u32 writes (coalesced)
        uint* cc = (uint*)catC + ((size_t)n * 200 + hf * 100) * 64;
        for (int e2 = tid; e2 < 6400; e2 += 256) {
            int r = e2 >> 6, c2 = e2 & 63;
            float f0 = smp[r * 129 + c2 * 2], f1 = smp[r * 129 + c2 * 2 + 1];
            cc[r * 64 + c2] = (uint)f2bf(f0) | ((uint)f2bf(f1) << 16);
        }
        // bf16 A-frag writes
        bool isSup = (n >= NQ);
        for (int o = tid; o < 1600; o += 256) {
            int k8 = o / 100, tt = o - k8 * 100;
            int base = tt * 129 + k8 * 8;
            uint4 pk;
            pk.x = (uint)f2bf(smp[base+0]) | ((uint)f2bf(smp[base+1]) << 16);
            pk.y = (uint)f2bf(smp[base+2]) | ((uint)f2bf(smp[base+3]) << 16);
            pk.z = (uint)f2bf(smp[base+4]) | ((uint)f2bf(smp[base+5]) << 16);
            pk.w = (uint)f2bf(smp[base+6]) | ((uint)f2bf(smp[base+7]) << 16);
            int row = n * 200 + hf * 100 + tt;
            size_t dst = (((size_t)(row >> 5) * 8 + (k8 >> 1)) * 64 + ((row & 31) + 32 * (k8 & 1))) * 8;
            *(uint4*)(catQbf + dst) = pk;
            if (isSup) {
                int r2 = (n - NQ) * 200 + hf * 100 + tt;
                size_t dst2 = (((size_t)(r2 >> 5) * 8 + (k8 >> 1)) * 64 + ((r2 & 31) + 32 * (k8 & 1))) * 8;
                *(uint4*)(catSbf + dst2) = pk;
            }
        }
    } else if (b < 204) {
        int wi = b - 200;
        const float* W = (wi == 0) ? Wq : (wi == 1) ? Wk : (wi == 2) ? Wv : Wo;
        ushort* dstW = Wfrag + (size_t)wi * 16384;
        for (int o = tid; o < 2048; o += 256) {
            int k8 = o >> 7, c = o & 127;
            uint4 pk;
            float f0 = W[(k8*8+0)*128 + c], f1 = W[(k8*8+1)*128 + c];
            float f2 = W[(k8*8+2)*128 + c], f3 = W[(k8*8+3)*128 + c];
            float f4 = W[(k8*8+4)*128 + c], f5 = W[(k8*8+5)*128 + c];
            float f6 = W[(k8*8+6)*128 + c], f7 = W[(k8*8+7)*128 + c];
            pk.x = (uint)f2bf(f0) | ((uint)f2bf(f1) << 16);
            pk.y = (uint)f2bf(f2) | ((uint)f2bf(f3) << 16);
            pk.z = (uint)f2bf(f4) | ((uint)f2bf(f5) << 16);
            pk.w = (uint)f2bf(f6) | ((uint)f2bf(f7) << 16);
            size_t dst = ((size_t)((c >> 5) * 8 + (k8 >> 1)) * 64 + ((c & 31) + 32 * (k8 & 1))) * 8;
            *(uint4*)(dstW + dst) = pk;
        }
        if (wi == 3) {
            uint4 z = make_uint4(0, 0, 0, 0);
            for (int o = tid; o < 512; o += 256) {
                int ks = o >> 6, l = o & 63;
                if ((l & 31) >= 8)
                    *(uint4*)(catSbf + (((size_t)156 * 8 + ks) * 64 + l) * 8) = z;
            }
        }
    } else {
        for (int i = tid; i < NCLS * ROW; i += 256) proto[i] = 0.f;
        if (tid == 0) *counter = 0;
    }
}

// ============ kernel 2: projections via MFMA ============
__global__ __launch_bounds__(256) void k_proj(
    const ushort* __restrict__ catQbf, const ushort* __restrict__ catSbf,
    const ushort* __restrict__ Wfrag, const float* __restrict__ bq,
    const float* __restrict__ bk, const float* __restrict__ bv,
    ushort* __restrict__ Qf, ushort* __restrict__ Kf, ushort* __restrict__ Vf) {
    __shared__ ushort Vt[128 * 136];
    int b = blockIdx.x, tid = threadIdx.x;
    int w = tid >> 6, lane = tid & 63;
    int typ, rb0, nrb;
    if (b < 157)      { typ = 0; rb0 = b * 4;         nrb = RB_Q; }
    else if (b < 197) { typ = 1; rb0 = (b - 157) * 4; nrb = RB_S; }
    else              { typ = 2; rb0 = (b - 197) * 4; nrb = RB_S; }
    int rowblk = rb0 + w;
    bool act = rowblk < nrb;
    const ushort* src = (typ == 0) ? catQbf : catSbf;
    const ushort* Wf = Wfrag + (size_t)typ * 16384;
    const float* bias = (typ == 0) ? bq : (typ == 1) ? bk : bv;
    int rlimit = (typ == 0) ? ROWS_Q : ROWS_S;

    short8 af[8];
    if (act) {
        const ushort* ap = src + (size_t)rowblk * 4096 + lane * 8;
        #pragma unroll
        for (int ks = 0; ks < 8; ++ks) af[ks] = *(const short8*)(ap + ks * 512);
    }
    #pragma unroll
    for (int ct = 0; ct < 4; ++ct) {
        f32x16 Cm;
        #pragma unroll
        for (int r = 0; r < 16; ++r) Cm[r] = 0.f;
        if (act) {
            const ushort* bp = Wf + (size_t)(ct * 8) * 512 + lane * 8;
            #pragma unroll
            for (int ks = 0; ks < 8; ++ks) {
                short8 bf_ = *(const short8*)(bp + ks * 512);
                Cm = __builtin_amdgcn_mfma_f32_32x32x16_bf16(af[ks], bf_, Cm, 0, 0, 0);
            }
            float bcol = bias[ct * 32 + (lane & 31)];
            if (typ <= 1) {
                ushort* dstB = (typ == 0) ? Qf : Kf;
                #pragma unroll
                for (int r = 0; r < 16; ++r) {
                    int row = rowblk * 32 + (r & 3) + 8 * (r >> 2) + 4 * (lane >> 5);
                    if (row < rlimit) {
                        int c = ct * 32 + (lane & 31);
                        int st = row / 25, vv = row - st * 25;
                        size_t dst = (((size_t)st * 8 + (c >> 4)) * 64 + (vv + 32 * ((c >> 3) & 1))) * 8 + (c & 7);
                        dstB[dst] = f2bf(Cm[r] + bcol);
                    }
                }
            } else {
                #pragma unroll
                for (int r = 0; r < 16; ++r) {
                    int lrow = w * 32 + (r & 3) + 8 * (r >> 2) + 4 * (lane >> 5);
                    Vt[lrow * 136 + ct * 32 + (lane & 31)] = f2bf(Cm[r] + bcol);
                }
            }
        }
    }
    if (typ == 2) {
        __syncthreads();
        const ushort* WoF = Wfrag + (size_t)3 * 16384;
        short8 a2[8];
        if (act) {
            #pragma unroll
            for (int ks = 0; ks < 8; ++ks)
                a2[ks] = *(const short8*)(Vt + (w * 32 + (lane & 31)) * 136 + ks * 16 + (lane >> 5) * 8);
        }
        #pragma unroll
        for (int ct = 0; ct < 4; ++ct) {
            if (act) {
                f32x16 Cm;
                #pragma unroll
                for (int r = 0; r < 16; ++r) Cm[r] = 0.f;
                const ushort* bp = WoF + (size_t)(ct * 8) * 512 + lane * 8;
                #pragma unroll
                for (int ks = 0; ks < 8; ++ks) {
                    short8 bf_ = *(const short8*)(bp + ks * 512);
                    Cm = __builtin_amdgcn_mfma_f32_32x32x16_bf16(a2[ks], bf_, Cm, 0, 0, 0);
                }
                #pragma unroll
                for (int r = 0; r < 16; ++r) {
                    int row = rowblk * 32 + (r & 3) + 8 * (r >> 2) + 4 * (lane >> 5);
                    if (row < ROWS_S) {
                        int c = ct * 32 + (lane & 31);
                        int tile = row / 25, vv = row - tile * 25;
                        size_t dst = ((((size_t)tile * 4 + ct) * 2 + (vv >> 4)) * 64
                                      + ((c & 31) + 32 * ((vv & 15) >> 3))) * 8 + (vv & 7);
                        Vf[dst] = f2bf(Cm[r]);
                    }
                }
            }
        }
    }
}

// ============ kernel 3: MFMA fused attention + residual + LN ============
// 800 blocks = one per (n,t); 4 waves split m 7/6/6/6; no barriers in m-loop.
// launch_bounds(256,2): unified VGPR+AGPR cap 256 — (256,3) spilled (R4: VGPR 84,
// FETCH 200 MB scratch traffic). Q-frags live in LDS (shared by all 4 waves);
// K-frags double-buffered in regs (prefetch next m during LN).
__global__ __launch_bounds__(256, 2) void k_attn(
    const ushort* __restrict__ Qf, const ushort* __restrict__ Kf,
    const ushort* __restrict__ Vf, const ushort* __restrict__ catC,
    const float* __restrict__ bo, float* __restrict__ att,
    float* __restrict__ proto) {
    __shared__ float catb[25 * 129];          // stride 129: conflict-free scalar reads
    __shared__ float red[2][50][65];          // reduce scratch; ALIASED by pfrag in m-loop
    __shared__ ushort qls[4096];              // Q-frag tile (same for all 4 waves)
    ushort* pfragU = (ushort*)red;            // [4 wv][2 ks][64 lane][8] = 8 KB < 26 KB

    int pair = blockIdx.x;                    // n*8 + t
    int n = pair >> 3, t = pair & 7;
    int tid = threadIdx.x;
    int wv = tid >> 6, lane = tid & 63;
    int q = lane & 31, half = lane >> 5;

    // stage residual tile: catb = bf16(catC) + bo
    {
        const uint* cc = (const uint*)catC + (size_t)pair * 1600;
        for (int i2 = tid; i2 < 1600; i2 += 256) {
            uint u = cc[i2];
            int r = i2 >> 6, c2 = (i2 & 63) * 2;
            catb[r * 129 + c2]     = bf2f(u & 0xffffu) + bo[c2];
            catb[r * 129 + c2 + 1] = bf2f(u >> 16) + bo[c2 + 1];
        }
    }
    // stage Q-frag tile
    {
        const uint* qp = (const uint*)(Qf + (size_t)pair * 4096);
        uint* ql = (uint*)qls;
        for (int i2 = tid; i2 < 2048; i2 += 256) ql[i2] = qp[i2];
    }
    // zero this wave's P-frag (aliased memory; key>=25 slots stay 0)
    {
        uint4 z = make_uint4(0, 0, 0, 0);
        *(uint4*)&pfragU[(((wv * 2 + 0) * 64) + lane) * 8] = z;
        *(uint4*)&pfragU[(((wv * 2 + 1) * 64) + lane) * 8] = z;
    }
    __syncthreads();

    int qc = q < 25 ? q : 24;
    float attsum[64];
    #pragma unroll
    for (int i = 0; i < 64; ++i) attsum[i] = 0.f;
    float Csc = 0.f;                          // sum over m of (-mu*rs)

    const float CEXP = (float)(1.4426950408889634 * 0.08838834764831845);

    // preload K-frags for first m (prefetch overruns past Kf land in Vf region — safe, unused)
    const ushort* kbase = Kf + (size_t)t * 4096 + lane * 8;
    short8 kf[8];
    #pragma unroll
    for (int ks = 0; ks < 8; ++ks)
        kf[ks] = *(const short8*)(kbase + (size_t)wv * 32768 + ks * 512);

    for (int m = wv; m < 25; m += 4) {
        // ---- S^T = K . Q^T  (Q from LDS, K from prefetched regs) ----
        f32x16 S;
        #pragma unroll
        for (int r = 0; r < 16; ++r) S[r] = 0.f;
        #pragma unroll
        for (int ks = 0; ks < 8; ++ks) {
            short8 qv = *(const short8*)(qls + ks * 512 + lane * 8);
            S = __builtin_amdgcn_mfma_f32_32x32x16_bf16(kf[ks], qv, S, 0, 0, 0);
        }

        // ---- softmax over keys (in-lane + pair shuffle) ----
        float p[16], mx = -3e38f;
        #pragma unroll
        for (int r = 0; r < 16; ++r) {
            int key = (r & 3) + 8 * (r >> 2) + 4 * half;
            float v = (key < 25) ? S[r] : -3e38f;
            p[r] = v; mx = fmaxf(mx, v);
        }
        mx = fmaxf(mx, __shfl_xor(mx, 32));
        float sum = 0.f;
        #pragma unroll
        for (int r = 0; r < 16; ++r) { p[r] = exp2f((p[r] - mx) * CEXP); sum += p[r]; }
        sum += __shfl_xor(sum, 32);
        float inv = 1.f / sum;

        // ---- issue V loads now; pfrag LDS roundtrip covers their latency ----
        const ushort* vp = Vf + ((size_t)(m * 8 + t)) * 4096 + lane * 8;
        short8 vf0 = *(const short8*)(vp);
        short8 vf1 = *(const short8*)(vp + 512);
        short8 vf2 = *(const short8*)(vp + 1024);
        short8 vf3 = *(const short8*)(vp + 1536);
        short8 vf4 = *(const short8*)(vp + 2048);
        short8 vf5 = *(const short8*)(vp + 2560);
        short8 vf6 = *(const short8*)(vp + 3072);
        short8 vf7 = *(const short8*)(vp + 3584);

        // ---- P^T (C-layout) -> B-frag via wave-private LDS roundtrip ----
        #pragma unroll
        for (int r = 0; r < 16; ++r) {
            int key = (r & 3) + 8 * (r >> 2) + 4 * half;
            if (key < 25)
                pfragU[(((wv * 2 + (key >> 4)) * 64) + (q + 32 * ((key >> 3) & 1))) * 8 + (key & 7)]
                    = f2bf(p[r] * inv);
        }
        short8 pb0 = *(const short8*)&pfragU[(((wv * 2 + 0) * 64) + lane) * 8];
        short8 pb1 = *(const short8*)&pfragU[(((wv * 2 + 1) * 64) + lane) * 8];

        // ---- ctx^T = Vo^T . P^T ----
        f32x16 ctx[4];
        #pragma unroll
        for (int mt = 0; mt < 4; ++mt) {
            #pragma unroll
            for (int r = 0; r < 16; ++r) ctx[mt][r] = 0.f;
        }
        ctx[0] = __builtin_amdgcn_mfma_f32_32x32x16_bf16(vf0, pb0, ctx[0], 0, 0, 0);
        ctx[0] = __builtin_amdgcn_mfma_f32_32x32x16_bf16(vf1, pb1, ctx[0], 0, 0, 0);
        ctx[1] = __builtin_amdgcn_mfma_f32_32x32x16_bf16(vf2, pb0, ctx[1], 0, 0, 0);
        ctx[1] = __builtin_amdgcn_mfma_f32_32x32x16_bf16(vf3, pb1, ctx[1], 0, 0, 0);
        ctx[2] = __builtin_amdgcn_mfma_f32_32x32x16_bf16(vf4, pb0, ctx[2], 0, 0, 0);
        ctx[2] = __builtin_amdgcn_mfma_f32_32x32x16_bf16(vf5, pb1, ctx[2], 0, 0, 0);
        ctx[3] = __builtin_amdgcn_mfma_f32_32x32x16_bf16(vf6, pb0, ctx[3], 0, 0, 0);
        ctx[3] = __builtin_amdgcn_mfma_f32_32x32x16_bf16(vf7, pb1, ctx[3], 0, 0, 0);

        // ---- prefetch next m's K-frags (latency hidden under LN) ----
        short8 kfn[8];
        #pragma unroll
        for (int ks = 0; ks < 8; ++ks)
            kfn[ks] = *(const short8*)(kbase + (size_t)(m + 4) * 32768 + ks * 512);

        // ---- x = ctx + (cat + bo); LN; accumulate ----
        float s1 = 0.f, s2 = 0.f;
        #pragma unroll
        for (int mt = 0; mt < 4; ++mt) {
            #pragma unroll
            for (int r = 0; r < 16; ++r) {
                int c = mt * 32 + (r & 3) + 8 * (r >> 2) + 4 * half;
                float xv = ctx[mt][r] + catb[qc * 129 + c];
                ctx[mt][r] = xv;
                s1 += xv; s2 = fmaf(xv, xv, s2);
            }
        }
        s1 += __shfl_xor(s1, 32); s2 += __shfl_xor(s2, 32);
        float mu = s1 * (1.f / 128.f);
        float var = s2 * (1.f / 128.f) - mu * mu;
        var = fmaxf(var, 0.f);
        float rs = rsqrtf(var + 1e-12f);
        #pragma unroll
        for (int i = 0; i < 64; ++i)
            attsum[i] = fmaf(ctx[i >> 4][i & 15], rs, attsum[i]);
        Csc = fmaf(-mu, rs, Csc);

        #pragma unroll
        for (int ks = 0; ks < 8; ++ks) kf[ks] = kfn[ks];
    }

    // ---- 2-stage pairwise cross-wave reduction (compact: 50 live lanes) ----
    __syncthreads();   // all waves done with m-loop; pfrag alias now dead
    int s = half * 25 + q;
    bool act = q < 25;
    if ((wv == 1 || wv == 3) && act) {
        float (*rg)[65] = red[wv >> 1];
        #pragma unroll
        for (int i = 0; i < 64; ++i) rg[s][i] = attsum[i];
        rg[s][64] = Csc;
    }
    __syncthreads();
    if ((wv == 0 || wv == 2) && act) {
        float (*rg)[65] = red[wv >> 1];
        #pragma unroll
        for (int i = 0; i < 64; ++i) attsum[i] += rg[s][i];
        Csc += rg[s][64];
    }
    __syncthreads();
    if (wv == 2 && act) {
        #pragma unroll
        for (int i = 0; i < 64; ++i) red[0][s][i] = attsum[i];
        red[0][s][64] = Csc;
    }
    __syncthreads();
    if (wv == 0 && act) {
        #pragma unroll
        for (int i = 0; i < 64; ++i) attsum[i] += red[0][s][i];
        Csc += red[0][s][64];
        if (n < NQ) {
            float* ap = att + (size_t)pair * TILE + q * 128;
            #pragma unroll
            for (int mt = 0; mt < 4; ++mt) {
                #pragma unroll
                for (int rg4 = 0; rg4 < 4; ++rg4) {
                    int c0 = mt * 32 + 8 * rg4 + 4 * half;
                    int i0 = mt * 16 + rg4 * 4;
                    float4 o;
                    o.x = attsum[i0 + 0] + Csc; o.y = attsum[i0 + 1] + Csc;
                    o.z = attsum[i0 + 2] + Csc; o.w = attsum[i0 + 3] + Csc;
                    *(float4*)&ap[c0] = o;
                }
            }
        } else {
            int cls = (n - NQ) / NSUP;
            float* pp = proto + (size_t)cls * ROW + t * TILE + q * 128;
            #pragma unroll
            for (int mt = 0; mt < 4; ++mt) {
                #pragma unroll
                for (int r = 0; r < 16; ++r) {
                    int c = mt * 32 + (r & 3) + 8 * (r >> 2) + 4 * half;
                    atomicAdd(&pp[c], (attsum[mt * 16 + r] + Csc) * 0.2f);
                }
            }
        }
    }
}

// ============ kernel 4: fused distances + log-softmax loss/acc ============
// 375 blocks, one per (query, class). Last block (atomic ticket) computes loss.
__global__ __launch_bounds__(256) void k_dist_loss(
    const float* __restrict__ att, const float* __restrict__ proto,
    const float* __restrict__ ln_g, float* __restrict__ dist,
    int* __restrict__ counter, float* __restrict__ out) {
    int b = blockIdx.x;
    int i = b / 5, j = b - 5 * i;
    const float4* a = (const float4*)(att + (size_t)i * ROW);
    const float4* p = (const float4*)(proto + (size_t)j * ROW);
    float d = 0.f;
    for (int e4 = threadIdx.x; e4 < 6400; e4 += 256) {
        float4 av = a[e4], pv = p[e4];
        float4 g4 = *(const float4*)(ln_g + (e4 & 31) * 4);
        float dx = av.x - pv.x, dy = av.y - pv.y;
        float dz = av.z - pv.z, dw = av.w - pv.w;
        d = fmaf(g4.x * g4.x, dx * dx, d);
        d = fmaf(g4.y * g4.y, dy * dy, d);
        d = fmaf(g4.z * g4.z, dz * dz, d);
        d = fmaf(g4.w * g4.w, dw * dw, d);
    }
    #pragma unroll
    for (int msk = 32; msk >= 1; msk >>= 1) d += __shfl_xor(d, msk);
    __shared__ float part[4];
    __shared__ int lastFlag;
    int lane = threadIdx.x & 63, wv = threadIdx.x >> 6;
    if (lane == 0) part[wv] = d;
    __syncthreads();
    if (threadIdx.x == 0) {
        float total = (part[0] + part[1] + part[2] + part[3]) * (1.f / 625.f);
        __hip_atomic_store(&dist[b], total, __ATOMIC_RELEASE, __HIP_MEMORY_SCOPE_AGENT);
        int tk = __hip_atomic_fetch_add(counter, 1, __ATOMIC_ACQ_REL, __HIP_MEMORY_SCOPE_AGENT);
        lastFlag = (tk == 374);
    }
    __syncthreads();
    if (!lastFlag) return;

    // last block: loss + accuracy over the 375 dists
    int iq = threadIdx.x;   // 75 active
    float li = 0.f, ok = 0.f;
    if (iq < NQ) {
        float dd[5];
        #pragma unroll
        for (int jj = 0; jj < 5; ++jj)
            dd[jj] = __hip_atomic_load(&dist[iq * 5 + jj], __ATOMIC_ACQUIRE, __HIP_MEMORY_SCOPE_AGENT);
        int cls = iq / NQRY;
        float mind = dd[0];
        int best = 0;
        #pragma unroll
        for (int jj = 1; jj < 5; ++jj) {
            if (dd[jj] < mind) mind = dd[jj];
            if (dd[jj] < dd[best]) best = jj;   // first-min == argmax(-d)
        }
        float sume = 0.f;
        #pragma unroll
        for (int jj = 0; jj < 5; ++jj) sume += expf(mind - dd[jj]);
        float lse = logf(sume) - mind;
        li = dd[cls] + lse;
        ok = (best == cls) ? 1.f : 0.f;
    }
    #pragma unroll
    for (int msk = 32; msk >= 1; msk >>= 1) {
        li += __shfl_xor(li, msk);
        ok += __shfl_xor(ok, msk);
    }
    if (lane == 0) { part[wv] = li; part[wv + 2] = ok; }  // wv 0,1 only hold active lanes
    __syncthreads();
    if (threadIdx.x == 0) {
        out[0] = (part[0] + part[1]) / 75.f;
        out[1] = (part[2] + part[3]) / 75.f;
    }
}

extern "C" void kernel_launch(void* const* d_in, const int* in_sizes, int n_in,
                              void* d_out, int out_size, void* d_ws, size_t ws_size,
                              hipStream_t stream) {
    const float* input = (const float*)d_in[0];
    const float* Wq   = (const float*)d_in[1];
    const float* bq   = (const float*)d_in[2];
    const float* Wk   = (const float*)d_in[3];
    const float* bk   = (const float*)d_in[4];
    const float* Wv   = (const float*)d_in[5];
    const float* bv   = (const float*)d_in[6];
    const float* Wo   = (const float*)d_in[7];
    const float* bo   = (const float*)d_in[8];
    const float* ln_g = (const float*)d_in[9];
    const float* ln_b = (const float*)d_in[10];  // cancels in the distance
    const int* target = (const int*)d_in[11];
    float* out = (float*)d_out;
    (void)ln_b;

    float* ws = (float*)d_ws;
    ushort* catQbf = (ushort*)ws;                            // 2,560,000 u16
    ushort* catSbf = catQbf + (size_t)RB_Q * 4096;           //   643,072
    ushort* Wfrag  = catSbf + (size_t)RB_S * 4096;           //    65,536
    ushort* catC   = Wfrag + 65536;                          // 2,560,000
    ushort* Qf     = catC + 2560000;                         // 3,276,800
    ushort* Kf     = Qf + 3276800;                           //   819,200
    ushort* Vf     = Kf + 819200;                            //   819,200 (also prefetch overrun pad)
    float*  att    = (float*)(Vf + 819200);                  // 75*25600 fp32
    float*  proto  = att + 1920000;                          // 128,000
    float*  distb  = proto + 128000;                         // 375
    int*    counter= (int*)(distb + 512);
    // total ~29.7 MB

    k_prep<<<205, 256, 0, stream>>>(input, target, Wq, Wk, Wv, Wo,
                                    catQbf, catSbf, Wfrag, catC, proto, counter);
    k_proj<<<237, 256, 0, stream>>>(catQbf, catSbf, Wfrag, bq, bk, bv, Qf, Kf, Vf);
    k_attn<<<800, 256, 0, stream>>>(Qf, Kf, Vf, catC, bo, att, proto);
    k_dist_loss<<<375, 256, 0, stream>>>(att, proto, ln_g, distb, counter, out);
}